// Round 4
// baseline (607.253 us; speedup 1.0000x reference)
//
#include <hip/hip_runtime.h>
#include <cstdint>

// Problem constants (fixed by the reference setup_inputs)
#define BB    2
#define LL    2048
#define HH    8
#define EE    64
#define DIAG  64
#define RR    16         // output rows per block
#define WCAP  144        // staged window rows: [i0-64, i0+80)
#define SK    68         // padded LDS row stride (floats) for K/V tile
#define PSK   148        // padded LDS row stride (floats) for probs
#define NT    256        // threads per block (4 waves)

// One 256-thread block per 16 consecutive rows of one (b,h). 2048 blocks.
__global__ __launch_bounds__(NT, 3) void anomaly_attn_kernel(
    const float* __restrict__ Q,   // [B, L, H, E]
    const float* __restrict__ K,   // [B, L, H, E]
    const float* __restrict__ V,   // [B, L, H, E]
    float* __restrict__ outV,      // [B, L, H, E]
    float* __restrict__ outS)      // [B, H, L, L]
{
    __shared__ float lds_kv[WCAP * SK];   // K tile, later reused as V tile (38.3 KB)
    __shared__ float lds_q[RR * EE];      // Q tile (4 KB)
    __shared__ float lds_p[RR * PSK];     // probs, absolute-window layout (9.25 KB)

    // XCD swizzle: contiguous row-blocks per XCD for L2 locality.
    const int bid  = blockIdx.x;
    const int gblk = (bid & 7) * 256 + (bid >> 3);   // [0, 2048)
    const int rb   = gblk & 127;
    const int h    = (gblk >> 7) & 7;
    const int b    = gblk >> 10;
    const int i0   = rb * RR;

    const int t    = threadIdx.x;
    const int wave = t >> 6;
    const int lane = t & 63;

    const size_t headOff = ((size_t)b * LL * HH + h) * EE;
    const int    rowStr  = HH * EE;   // 512 floats between sequence rows

    // Band window (block-uniform): columns [wstart, wend) may be nonzero.
    const int j0      = i0 - DIAG;               // unclamped window start
    const int wstart  = j0 < 0 ? 0 : j0;
    int       wend    = i0 + 80; if (wend > LL) wend = LL;
    const int width4  = (wend - wstart) >> 2;    // 20..36 float4s
    const int wstart4 = wstart >> 2;
    const int zf4     = (LL >> 2) - width4;      // zero float4s per row

    float* srow0 = outS + (((size_t)(b * HH + h)) * LL + i0) * LL;

    // ---- Phase Z: fire-and-forget zero stores outside the band window. ----
    // Issued before any load/barrier so the HBM write stream drains under
    // all subsequent compute. Never overlaps the band region (no WAW).
    {
        const float4 z = make_float4(0.f, 0.f, 0.f, 0.f);
        for (int row = 0; row < RR; ++row) {
            float4* srow4 = (float4*)(srow0 + (size_t)row * LL);
            for (int c = t; c < zf4; c += NT) {
                const int col4 = c < wstart4 ? c : c + width4;
                srow4[col4] = z;
            }
        }
    }

    // ---- Phase A: stage Q tile + K window (rows clamped; masked later) ----
    {
        const int qrow = t >> 4, qf = t & 15;
        *(float4*)(lds_q + qrow * EE + qf * 4) =
            *(const float4*)(Q + headOff + (size_t)(i0 + qrow) * rowStr + qf * 4);
        for (int idx = t; idx < WCAP * 16; idx += NT) {
            const int trow = idx >> 4, tf = idx & 15;
            int j = j0 + trow; j = j < 0 ? 0 : (j > LL - 1 ? LL - 1 : j);
            *(float4*)(lds_kv + trow * SK + tf * 4) =
                *(const float4*)(K + headOff + (size_t)j * rowStr + tf * 4);
        }
    }
    __syncthreads();

    // ---- Phase B: scores + softmax. Wave w owns rows 4w..4w+3.          ----
    // Absolute-j GEMM: lane owns window cols {lane, lane+64, 128+(lane&15)};
    // each K row is read ONCE and reused across the wave's 4 output rows.
    {
        float sa[4] = {0,0,0,0}, sb[4] = {0,0,0,0}, sc3[4] = {0,0,0,0};
        const float* ka = lds_kv + lane * SK;
        const float* kb = lds_kv + (lane + 64) * SK;
        const float* kc = lds_kv + (128 + (lane & 15)) * SK;
        const float* qb = lds_q + wave * 4 * EE;
#pragma unroll
        for (int c = 0; c < 16; ++c) {
            const float4 A  = *(const float4*)(ka + c * 4);
            const float4 Bv = *(const float4*)(kb + c * 4);
            const float4 Cv = *(const float4*)(kc + c * 4);
#pragma unroll
            for (int r = 0; r < 4; ++r) {
                const float4 q4 = *(const float4*)(qb + r * EE + c * 4);  // broadcast
                sa[r]  += q4.x * A.x  + q4.y * A.y  + q4.z * A.z  + q4.w * A.w;
                sb[r]  += q4.x * Bv.x + q4.y * Bv.y + q4.z * Bv.z + q4.w * Bv.w;
                sc3[r] += q4.x * Cv.x + q4.y * Cv.y + q4.z * Cv.z + q4.w * Cv.w;
            }
        }
        const float scale = 0.125f;   // 1/sqrt(64)
#pragma unroll
        for (int r = 0; r < 4; ++r) {
            const int rr = wave * 4 + r;       // row in tile; band jrel in [rr+1, rr+127]
            const bool va = (lane >= rr + 1) && (j0 + lane >= 0);
            const bool vb = (lane <= rr + 63) && (i0 + lane < LL);
            const bool vc = (lane < 16) && (lane <= rr - 1) && (i0 + DIAG + lane < LL);
            float As = va ? sa[r]  * scale : -3.0e38f;
            float Bs = vb ? sb[r]  * scale : -3.0e38f;
            float Cs = vc ? sc3[r] * scale : -3.0e38f;

            float m = fmaxf(As, fmaxf(Bs, Cs));
#pragma unroll
            for (int off = 1; off < 64; off <<= 1)
                m = fmaxf(m, __shfl_xor(m, off, 64));
            float pa = va ? __expf(As - m) : 0.f;
            float pb = vb ? __expf(Bs - m) : 0.f;
            float pc = vc ? __expf(Cs - m) : 0.f;
            float l = pa + pb + pc;
#pragma unroll
            for (int off = 1; off < 64; off <<= 1)
                l += __shfl_xor(l, off, 64);
            const float inv = 1.0f / l;
            lds_p[rr * PSK + lane]       = pa * inv;   // jrel = lane
            lds_p[rr * PSK + 64 + lane]  = pb * inv;   // jrel = 64+lane
            if (lane < 16)
                lds_p[rr * PSK + 128 + lane] = pc * inv;  // jrel = 128+lane
        }
    }
    __syncthreads();

    // ---- Phase D: band-window stores (coalesced f4 from lds_p) ----
    {
        const int woff4 = wstart4 - (j0 >> 2);   // lds_p f4 offset of wstart
        const int total = RR * width4;
        for (int idx = t; idx < total; idx += NT) {
            const int row = idx / width4;
            const int c   = idx - row * width4;
            const float4 v = *(const float4*)(lds_p + row * PSK + (woff4 + c) * 4);
            ((float4*)(srow0 + (size_t)row * LL))[wstart4 + c] = v;
        }
    }

    // ---- Phase A2: stage V window over lds_kv ----
    for (int idx = t; idx < WCAP * 16; idx += NT) {
        const int trow = idx >> 4, tf = idx & 15;
        int j = j0 + trow; j = j < 0 ? 0 : (j > LL - 1 ? LL - 1 : j);
        *(float4*)(lds_kv + trow * SK + tf * 4) =
            *(const float4*)(V + headOff + (size_t)j * rowStr + tf * 4);
    }
    __syncthreads();

    // ---- Phase E: O[r,:] = sum_jrel P[r][jrel] * V[jrel,:]              ----
    // Lane = (jsub = lane>>4, e4 = lane&15); each V float4 read once,
    // reused for the wave's 4 rows with scalar P broadcasts.
    {
        const int e4   = lane & 15;
        const int jsub = lane >> 4;
        float4 a0 = make_float4(0,0,0,0), a1 = a0, a2 = a0, a3 = a0;
        const float* pr = lds_p + (wave * 4) * PSK;
#pragma unroll
        for (int k = 0; k < WCAP / 4; ++k) {
            const int jrel = jsub + 4 * k;
            const float4 vv = *(const float4*)(lds_kv + jrel * SK + e4 * 4);
            const float w0 = pr[jrel];
            const float w1 = pr[PSK + jrel];
            const float w2 = pr[2 * PSK + jrel];
            const float w3 = pr[3 * PSK + jrel];
            a0.x += w0 * vv.x; a0.y += w0 * vv.y; a0.z += w0 * vv.z; a0.w += w0 * vv.w;
            a1.x += w1 * vv.x; a1.y += w1 * vv.y; a1.z += w1 * vv.z; a1.w += w1 * vv.w;
            a2.x += w2 * vv.x; a2.y += w2 * vv.y; a2.z += w2 * vv.z; a2.w += w2 * vv.w;
            a3.x += w3 * vv.x; a3.y += w3 * vv.y; a3.z += w3 * vv.z; a3.w += w3 * vv.w;
        }
#pragma unroll
        for (int off = 16; off <= 32; off <<= 1) {
            a0.x += __shfl_xor(a0.x, off, 64); a0.y += __shfl_xor(a0.y, off, 64);
            a0.z += __shfl_xor(a0.z, off, 64); a0.w += __shfl_xor(a0.w, off, 64);
            a1.x += __shfl_xor(a1.x, off, 64); a1.y += __shfl_xor(a1.y, off, 64);
            a1.z += __shfl_xor(a1.z, off, 64); a1.w += __shfl_xor(a1.w, off, 64);
            a2.x += __shfl_xor(a2.x, off, 64); a2.y += __shfl_xor(a2.y, off, 64);
            a2.z += __shfl_xor(a2.z, off, 64); a2.w += __shfl_xor(a2.w, off, 64);
            a3.x += __shfl_xor(a3.x, off, 64); a3.y += __shfl_xor(a3.y, off, 64);
            a3.z += __shfl_xor(a3.z, off, 64); a3.w += __shfl_xor(a3.w, off, 64);
        }
        if (lane < 16) {
            float4* o0 = (float4*)(outV + headOff + (size_t)(i0 + wave * 4 + 0) * rowStr);
            float4* o1 = (float4*)(outV + headOff + (size_t)(i0 + wave * 4 + 1) * rowStr);
            float4* o2 = (float4*)(outV + headOff + (size_t)(i0 + wave * 4 + 2) * rowStr);
            float4* o3 = (float4*)(outV + headOff + (size_t)(i0 + wave * 4 + 3) * rowStr);
            o0[e4] = a0; o1[e4] = a1; o2[e4] = a2; o3[e4] = a3;
        }
    }
}

extern "C" void kernel_launch(void* const* d_in, const int* in_sizes, int n_in,
                              void* d_out, int out_size, void* d_ws, size_t ws_size,
                              hipStream_t stream) {
    const float* Q = (const float*)d_in[0];
    const float* K = (const float*)d_in[1];
    const float* V = (const float*)d_in[2];
    // d_in[3] = sigma (unused by reference), d_in[4] = attn_mask (unused)

    float* outV = (float*)d_out;                                   // [B,L,H,E]
    float* outS = (float*)d_out + (size_t)BB * LL * HH * EE;       // [B,H,L,L]

    const int grid = (BB * HH * LL) / RR;  // 2048 blocks
    anomaly_attn_kernel<<<grid, NT, 0, stream>>>(Q, K, V, outV, outS);
}

// Round 5
// 606.285 us; speedup vs baseline: 1.0016x; 1.0016x over previous
//
#include <hip/hip_runtime.h>
#include <cstdint>

// Problem constants (fixed by the reference setup_inputs)
#define BB    2
#define LL    2048
#define HH    8
#define EE    64
#define DIAG  64
#define RR    16         // output rows per block
#define WCAP  144        // staged window rows: [i0-64, i0+80)
#define SK    68         // padded LDS row stride (floats) for K/V tile
#define PSK   148        // padded LDS row stride (floats) for probs
#define NT    256        // threads per block (4 waves)

// One 256-thread block per 16 consecutive rows of one (b,h). 2048 blocks.
// Write discipline (R4 lesson): every outS cache line is written exactly once,
// by one wave, in one temporally-compact full-row pass — no split zero/band
// passes (they caused RMW amplification: WRITE 270->780 MB, FETCH 12->618 MB).
__global__ __launch_bounds__(NT, 3) void anomaly_attn_kernel(
    const float* __restrict__ Q,   // [B, L, H, E]
    const float* __restrict__ K,   // [B, L, H, E]
    const float* __restrict__ V,   // [B, L, H, E]
    float* __restrict__ outV,      // [B, L, H, E]
    float* __restrict__ outS)      // [B, H, L, L]
{
    __shared__ float lds_kv[WCAP * SK];   // K tile, later reused as V tile (38.3 KB)
    __shared__ float lds_q[RR * EE];      // Q tile (4 KB)
    __shared__ float lds_p[RR * PSK];     // probs, absolute-window layout (9.25 KB)

    // XCD swizzle: contiguous row-blocks per XCD for L2 locality of the
    // K/V windows (9x inter-block reuse) and the outS write stream.
    const int bid  = blockIdx.x;
    const int gblk = (bid & 7) * 256 + (bid >> 3);   // [0, 2048)
    const int rb   = gblk & 127;
    const int h    = (gblk >> 7) & 7;
    const int b    = gblk >> 10;
    const int i0   = rb * RR;

    const int t    = threadIdx.x;
    const int wave = t >> 6;
    const int lane = t & 63;

    const size_t headOff = ((size_t)b * LL * HH + h) * EE;
    const int    rowStr  = HH * EE;   // 512 floats between sequence rows

    const int j0      = i0 - DIAG;             // window start (may be < 0)
    const int j04     = j0 >> 2;               // arithmetic shift ok
    const int wstart4 = j0 < 0 ? 0 : (j0 >> 2);
    int       wend    = i0 + 80; if (wend > LL) wend = LL;
    const int wend4   = wend >> 2;

    float* srow0 = outS + (((size_t)(b * HH + h)) * LL + i0) * LL;

    // ---- Phase A: stage Q tile + K window (rows clamped; masked in B) ----
    {
        const int qrow = t >> 4, qf = t & 15;
        *(float4*)(lds_q + qrow * EE + qf * 4) =
            *(const float4*)(Q + headOff + (size_t)(i0 + qrow) * rowStr + qf * 4);
        for (int idx = t; idx < WCAP * 16; idx += NT) {
            const int trow = idx >> 4, tf = idx & 15;
            int j = j0 + trow; j = j < 0 ? 0 : (j > LL - 1 ? LL - 1 : j);
            *(float4*)(lds_kv + trow * SK + tf * 4) =
                *(const float4*)(K + headOff + (size_t)j * rowStr + tf * 4);
        }
    }
    __syncthreads();

    // ---- Phase B: scores + softmax. Wave w owns rows 4w..4w+3.          ----
    // Absolute-j GEMM: lane owns window cols {lane, lane+64, 128+(lane&15)};
    // each K row read ONCE per wave, reused across the wave's 4 output rows.
    {
        float sa[4] = {0,0,0,0}, sb[4] = {0,0,0,0}, sc3[4] = {0,0,0,0};
        const float* ka = lds_kv + lane * SK;
        const float* kb = lds_kv + (lane + 64) * SK;
        const float* kc = lds_kv + (128 + (lane & 15)) * SK;
        const float* qb = lds_q + wave * 4 * EE;
#pragma unroll
        for (int c = 0; c < 16; ++c) {
            const float4 A  = *(const float4*)(ka + c * 4);
            const float4 Bv = *(const float4*)(kb + c * 4);
            const float4 Cv = *(const float4*)(kc + c * 4);
#pragma unroll
            for (int r = 0; r < 4; ++r) {
                const float4 q4 = *(const float4*)(qb + r * EE + c * 4);  // broadcast
                sa[r]  += q4.x * A.x  + q4.y * A.y  + q4.z * A.z  + q4.w * A.w;
                sb[r]  += q4.x * Bv.x + q4.y * Bv.y + q4.z * Bv.z + q4.w * Bv.w;
                sc3[r] += q4.x * Cv.x + q4.y * Cv.y + q4.z * Cv.z + q4.w * Cv.w;
            }
        }
        const float scale = 0.125f;   // 1/sqrt(64)
#pragma unroll
        for (int r = 0; r < 4; ++r) {
            const int rr = wave * 4 + r;   // band jrel in [rr+1, rr+127]
            const bool va = (lane >= rr + 1) && (j0 + lane >= 0);
            const bool vb = (lane <= rr + 63) && (i0 + lane < LL);
            const bool vc = (lane < 16) && (lane <= rr - 1) && (i0 + DIAG + lane < LL);
            float As = va ? sa[r]  * scale : -3.0e38f;
            float Bs = vb ? sb[r]  * scale : -3.0e38f;
            float Cs = vc ? sc3[r] * scale : -3.0e38f;

            float m = fmaxf(As, fmaxf(Bs, Cs));
#pragma unroll
            for (int off = 1; off < 64; off <<= 1)
                m = fmaxf(m, __shfl_xor(m, off, 64));
            float pa = va ? __expf(As - m) : 0.f;
            float pb = vb ? __expf(Bs - m) : 0.f;
            float pc = vc ? __expf(Cs - m) : 0.f;
            float l = pa + pb + pc;
#pragma unroll
            for (int off = 1; off < 64; off <<= 1)
                l += __shfl_xor(l, off, 64);
            const float inv = 1.0f / l;
            lds_p[rr * PSK + lane]       = pa * inv;   // jrel = lane
            lds_p[rr * PSK + 64 + lane]  = pb * inv;   // jrel = 64+lane
            if (lane < 16)
                lds_p[rr * PSK + 128 + lane] = pc * inv;  // jrel = 128+lane
        }
    }
    __syncthreads();   // all waves done reading lds_kv (K)

    // ---- Phase A2: issue V-window loads into lds_kv (overwrites K).     ----
    // Issued BEFORE the big store stream so loads + stores are in flight
    // together; the next barrier drains both.
    for (int idx = t; idx < WCAP * 16; idx += NT) {
        const int trow = idx >> 4, tf = idx & 15;
        int j = j0 + trow; j = j < 0 ? 0 : (j > LL - 1 ? LL - 1 : j);
        *(float4*)(lds_kv + trow * SK + tf * 4) =
            *(const float4*)(V + headOff + (size_t)j * rowStr + tf * 4);
    }

    // ---- Phase D: stream full series rows (zeros + window), one pass.   ----
    // Each wave reads ONLY its own lds_p rows (written by itself in B), so
    // no barrier is needed before this — stores fire as early as possible.
    for (int r = 0; r < 4; ++r) {
        const int row = wave * 4 + r;
        float4* srow4 = (float4*)(srow0 + (size_t)row * LL);
        const float* prow = lds_p + row * PSK;
#pragma unroll
        for (int k = 0; k < 8; ++k) {
            const int col4  = lane + k * 64;
            const bool inwin = (col4 >= wstart4) && (col4 < wend4);
            float4 v = make_float4(0.f, 0.f, 0.f, 0.f);
            if (inwin) v = *(const float4*)(prow + (col4 - j04) * 4);
            srow4[col4] = v;
        }
    }
    __syncthreads();   // V tile staged (and this wave's loads/stores drained)

    // ---- Phase E: O[r,:] = sum_jrel P[r][jrel] * V[jrel,:]              ----
    // Lane = (jsub = lane>>4, e4 = lane&15); each V float4 read once,
    // reused for the wave's 4 rows with scalar P broadcasts.
    {
        const int e4   = lane & 15;
        const int jsub = lane >> 4;
        float4 a0 = make_float4(0,0,0,0), a1 = a0, a2 = a0, a3 = a0;
        const float* pr = lds_p + (wave * 4) * PSK;
#pragma unroll
        for (int k = 0; k < WCAP / 4; ++k) {
            const int jrel = jsub + 4 * k;
            const float4 vv = *(const float4*)(lds_kv + jrel * SK + e4 * 4);
            const float w0 = pr[jrel];
            const float w1 = pr[PSK + jrel];
            const float w2 = pr[2 * PSK + jrel];
            const float w3 = pr[3 * PSK + jrel];
            a0.x += w0 * vv.x; a0.y += w0 * vv.y; a0.z += w0 * vv.z; a0.w += w0 * vv.w;
            a1.x += w1 * vv.x; a1.y += w1 * vv.y; a1.z += w1 * vv.z; a1.w += w1 * vv.w;
            a2.x += w2 * vv.x; a2.y += w2 * vv.y; a2.z += w2 * vv.z; a2.w += w2 * vv.w;
            a3.x += w3 * vv.x; a3.y += w3 * vv.y; a3.z += w3 * vv.z; a3.w += w3 * vv.w;
        }
#pragma unroll
        for (int off = 16; off <= 32; off <<= 1) {
            a0.x += __shfl_xor(a0.x, off, 64); a0.y += __shfl_xor(a0.y, off, 64);
            a0.z += __shfl_xor(a0.z, off, 64); a0.w += __shfl_xor(a0.w, off, 64);
            a1.x += __shfl_xor(a1.x, off, 64); a1.y += __shfl_xor(a1.y, off, 64);
            a1.z += __shfl_xor(a1.z, off, 64); a1.w += __shfl_xor(a1.w, off, 64);
            a2.x += __shfl_xor(a2.x, off, 64); a2.y += __shfl_xor(a2.y, off, 64);
            a2.z += __shfl_xor(a2.z, off, 64); a2.w += __shfl_xor(a2.w, off, 64);
            a3.x += __shfl_xor(a3.x, off, 64); a3.y += __shfl_xor(a3.y, off, 64);
            a3.z += __shfl_xor(a3.z, off, 64); a3.w += __shfl_xor(a3.w, off, 64);
        }
        if (lane < 16) {
            float4* o0 = (float4*)(outV + headOff + (size_t)(i0 + wave * 4 + 0) * rowStr);
            float4* o1 = (float4*)(outV + headOff + (size_t)(i0 + wave * 4 + 1) * rowStr);
            float4* o2 = (float4*)(outV + headOff + (size_t)(i0 + wave * 4 + 2) * rowStr);
            float4* o3 = (float4*)(outV + headOff + (size_t)(i0 + wave * 4 + 3) * rowStr);
            o0[e4] = a0; o1[e4] = a1; o2[e4] = a2; o3[e4] = a3;
        }
    }
}

extern "C" void kernel_launch(void* const* d_in, const int* in_sizes, int n_in,
                              void* d_out, int out_size, void* d_ws, size_t ws_size,
                              hipStream_t stream) {
    const float* Q = (const float*)d_in[0];
    const float* K = (const float*)d_in[1];
    const float* V = (const float*)d_in[2];
    // d_in[3] = sigma (unused by reference), d_in[4] = attn_mask (unused)

    float* outV = (float*)d_out;                                   // [B,L,H,E]
    float* outS = (float*)d_out + (size_t)BB * LL * HH * EE;       // [B,H,L,L]

    const int grid = (BB * HH * LL) / RR;  // 2048 blocks
    anomaly_attn_kernel<<<grid, NT, 0, stream>>>(Q, K, V, outV, outS);
}